// Round 5
// baseline (313.135 us; speedup 1.0000x reference)
//
#include <hip/hip_runtime.h>
#include <math.h>

#define N_PTS 100000
#define P_PROP 256
#define R_FEAT 256
#define NCLS 21          // C + 1
#define NSEG 32          // segments of 3136 points (49 u64 mask words each)
#define SEG_LEN 3136     // 64-aligned; NSEG*SEG_LEN = 100352 >= N_PTS (pad bits = 0)
#define SEG_WORDS (SEG_LEN / 64)            // 49
#define BM_WORDS (NSEG * SEG_WORDS)         // 1568 u64 words per proposal
#define LIST_MAX 3136
#define FW_STRIDE 48     // padded bf16 channels per row: 21 cls | 21 obj | 6 pad = 96B
#define ACC_STRIDE 44    // 42 channel sums + 1 count + 1 pad
#define MTILE 128        // rows per featw block (4 waves x 2 x 16-row MFMA tiles)
#define FEATW_BLOCKS ((N_PTS + MTILE - 1) / MTILE)   // 782
#define NFRAG (3 * 8 * 64)   // B fragments: 3 N-tiles x 8 K-steps x 64 lanes
#define MASK_BLOCKS (NSEG * SEG_LEN / 256)  // 392
#define ROI_BLOCKS 4096      // each handles 2 segments of one proposal

typedef unsigned short u16t;
typedef unsigned int u32t;
typedef unsigned long long u64t;
typedef __attribute__((ext_vector_type(8))) short short8;   // 8 bf16 (4 VGPRs)
typedef __attribute__((ext_vector_type(4))) float f32x4;    // MFMA accumulator

__device__ __forceinline__ u16t f2bf_rne(float x) {
    u32t u = __float_as_uint(x);
    u += 0x7fffu + ((u >> 16) & 1u);
    return (u16t)(u >> 16);
}

// ---------------- Kernel A: featw (MFMA) + mask bitmap + gacc/done zero ----
// Round-4 lesson: totals are launch/overhead-dominated, so prep/mask/featw
// are fused into ONE launch of 1174 blocks. Blocks [0,782): fW = feats @
// [Wc|Wo|pad] via mfma_f32_16x16x32_bf16 (in-block B-frag build -- the
// separate prep launch was proven neutral in round 3). Blocks [782,1174):
// dense mask bitmap, one u64 ballot word per (proposal, 64-point wave);
// first mask block also zeroes gacc and the done counter for kernel B.
__global__ __launch_bounds__(256) void featw_mask_kernel(
    const float* __restrict__ proposals,   // (P,6)
    const float* __restrict__ xyz,         // (N,3)
    const float* __restrict__ feats,       // (N,R)
    const float* __restrict__ Wc,          // (R,21)
    const float* __restrict__ Wo,          // (R,21)
    u16t* __restrict__ fwb,                // (N,48) bf16
    float* __restrict__ gacc,              // (P,44) zeroed here
    u64t* __restrict__ bm,                 // (P, BM_WORDS)
    u32t* __restrict__ done)               // zeroed here
{
    const int t = threadIdx.x;

    if (blockIdx.x < FEATW_BLOCKS) {
        // ================= featw role =================
        __shared__ u16t bB[NFRAG * 8];     // 24 KiB of pre-swizzled B-frags

        for (int idx = t; idx < NFRAG; idx += 256) {
            const int n   = idx >> 9;         // N-tile 0..2
            const int rem = idx & 511;
            const int kk  = rem >> 6;         // K-step 0..7
            const int l   = rem & 63;         // lane
            const int krow = kk * 32 + (l >> 4) * 8;
            const int c    = n * 16 + (l & 15);
            u32t w[4];
#pragma unroll
            for (int jj = 0; jj < 4; ++jj) {
                const int k0 = krow + 2 * jj;
                float v0 = 0.0f, v1 = 0.0f;
                if (c < NCLS) {
                    v0 = Wc[k0 * NCLS + c];
                    v1 = Wc[(k0 + 1) * NCLS + c];
                } else if (c < 2 * NCLS) {
                    v0 = Wo[k0 * NCLS + (c - NCLS)];
                    v1 = Wo[(k0 + 1) * NCLS + (c - NCLS)];
                }
                w[jj] = (u32t)f2bf_rne(v0) | ((u32t)f2bf_rne(v1) << 16);
            }
            *(uint4*)(&bB[idx * 8]) = make_uint4(w[0], w[1], w[2], w[3]);
        }
        __syncthreads();

        const int wv = t >> 6;
        const int l  = t & 63;
        const int rowbase = blockIdx.x * MTILE + wv * 32;

        const int r0 = rowbase + (l & 15);
        const int r1 = r0 + 16;
        const int r0c = r0 < N_PTS ? r0 : N_PTS - 1;
        const int r1c = r1 < N_PTS ? r1 : N_PTS - 1;
        const float* __restrict__ a0p = feats + (size_t)r0c * R_FEAT + (l >> 4) * 8;
        const float* __restrict__ a1p = feats + (size_t)r1c * R_FEAT + (l >> 4) * 8;

        f32x4 c00 = {0.f,0.f,0.f,0.f}, c01 = {0.f,0.f,0.f,0.f}, c02 = {0.f,0.f,0.f,0.f};
        f32x4 c10 = {0.f,0.f,0.f,0.f}, c11 = {0.f,0.f,0.f,0.f}, c12 = {0.f,0.f,0.f,0.f};

#pragma unroll
        for (int kk = 0; kk < 8; ++kk) {
            const short8 b0 = *(const short8*)(&bB[((0 * 8 + kk) * 64 + l) * 8]);
            const short8 b1 = *(const short8*)(&bB[((1 * 8 + kk) * 64 + l) * 8]);
            const short8 b2 = *(const short8*)(&bB[((2 * 8 + kk) * 64 + l) * 8]);

            const float4 x0 = *(const float4*)(a0p + kk * 32);
            const float4 x1 = *(const float4*)(a0p + kk * 32 + 4);
            union { u32t u[4]; short8 s; } af0;
            af0.u[0] = (u32t)f2bf_rne(x0.x) | ((u32t)f2bf_rne(x0.y) << 16);
            af0.u[1] = (u32t)f2bf_rne(x0.z) | ((u32t)f2bf_rne(x0.w) << 16);
            af0.u[2] = (u32t)f2bf_rne(x1.x) | ((u32t)f2bf_rne(x1.y) << 16);
            af0.u[3] = (u32t)f2bf_rne(x1.z) | ((u32t)f2bf_rne(x1.w) << 16);
            c00 = __builtin_amdgcn_mfma_f32_16x16x32_bf16(af0.s, b0, c00, 0, 0, 0);
            c01 = __builtin_amdgcn_mfma_f32_16x16x32_bf16(af0.s, b1, c01, 0, 0, 0);
            c02 = __builtin_amdgcn_mfma_f32_16x16x32_bf16(af0.s, b2, c02, 0, 0, 0);

            const float4 y0 = *(const float4*)(a1p + kk * 32);
            const float4 y1 = *(const float4*)(a1p + kk * 32 + 4);
            union { u32t u[4]; short8 s; } af1;
            af1.u[0] = (u32t)f2bf_rne(y0.x) | ((u32t)f2bf_rne(y0.y) << 16);
            af1.u[1] = (u32t)f2bf_rne(y0.z) | ((u32t)f2bf_rne(y0.w) << 16);
            af1.u[2] = (u32t)f2bf_rne(y1.x) | ((u32t)f2bf_rne(y1.y) << 16);
            af1.u[3] = (u32t)f2bf_rne(y1.z) | ((u32t)f2bf_rne(y1.w) << 16);
            c10 = __builtin_amdgcn_mfma_f32_16x16x32_bf16(af1.s, b0, c10, 0, 0, 0);
            c11 = __builtin_amdgcn_mfma_f32_16x16x32_bf16(af1.s, b1, c11, 0, 0, 0);
            c12 = __builtin_amdgcn_mfma_f32_16x16x32_bf16(af1.s, b2, c12, 0, 0, 0);
        }

        const int ocol = l & 15;
        const int or0  = rowbase + (l >> 4) * 4;
#pragma unroll
        for (int j = 0; j < 4; ++j) {
            const int ra = or0 + j;
            if (ra < N_PTS) {
                u16t* __restrict__ orow = fwb + (size_t)ra * FW_STRIDE;
                orow[ocol]      = f2bf_rne(c00[j]);
                orow[ocol + 16] = f2bf_rne(c01[j]);
                orow[ocol + 32] = f2bf_rne(c02[j]);
            }
            const int rb = or0 + 16 + j;
            if (rb < N_PTS) {
                u16t* __restrict__ orow = fwb + (size_t)rb * FW_STRIDE;
                orow[ocol]      = f2bf_rne(c10[j]);
                orow[ocol + 16] = f2bf_rne(c11[j]);
                orow[ocol + 32] = f2bf_rne(c12[j]);
            }
        }
        return;
    }

    // ================= mask role =================
    const int mb = blockIdx.x - FEATW_BLOCKS;   // 0..391
    if (mb == 0) {
        for (int i = t; i < P_PROP * ACC_STRIDE; i += 256) gacc[i] = 0.0f;
        if (t == 0) *done = 0u;
    }

    __shared__ float4 plohi[P_PROP][2];    // [0]=lox,loy,loz,hix  [1]=hiy,hiz,-,-
    for (int pp = t; pp < P_PROP; pp += 256) {
        const float cx = proposals[pp * 6 + 0];
        const float cy = proposals[pp * 6 + 1];
        const float cz = proposals[pp * 6 + 2];
        const float hx = proposals[pp * 6 + 3] * 0.5f;
        const float hy = proposals[pp * 6 + 4] * 0.5f;
        const float hz = proposals[pp * 6 + 5] * 0.5f;
        plohi[pp][0] = make_float4(cx - hx, cy - hy, cz - hz, cx + hx);
        plohi[pp][1] = make_float4(cy + hy, cz + hz, 0.0f, 0.0f);
    }
    __syncthreads();

    const int i = mb * 256 + t;
    const bool alive = i < N_PTS;
    const int ic = alive ? i : 0;
    const float xx = xyz[ic * 3 + 0];
    const float yy = xyz[ic * 3 + 1];
    const float zz = xyz[ic * 3 + 2];
    const int lane = t & 63;
    const int iw = mb * 4 + (t >> 6);      // global u64 word index for this wave

#pragma unroll 8
    for (int p = 0; p < P_PROP; ++p) {
        const float4 a = plohi[p][0];
        const float4 b = plohi[p][1];
        const bool in = alive &
                        (xx >= a.x) & (xx <= a.w) &
                        (yy >= a.y) & (yy <= b.x) &
                        (zz >= a.z) & (zz <= b.y);
        const u64t msk = __ballot(in);
        if (lane == 0) bm[(size_t)p * BM_WORDS + iw] = msk;
    }
}

// ---------------- Kernel B: bitmap gather + atomic combine + fused softmax -
// grid = 4096: x = bid&7 (XCD), p = (bid>>3)&255, q = bid>>11; each block
// gathers TWO segments s = q*16 + h*8 + x (h=0,1) of proposal p -- same-XCD
// fW windows (4 x 300KB per XCD, L2-resident). Per segment: 392B bitmap ->
// LDS compaction -> lane-per-dword-pair gather (8 rows in flight). One set
// of 43 gacc atomics per block. Epilogue: t0 does threadfence + done-count;
// the LAST block re-reads gacc with AGENT-scope atomic loads (other XCDs'
// L2s may hold stale zeroed lines -- G16) and runs the proven softmax.
__global__ __launch_bounds__(256) void roi_softmax_kernel(
    const u64t* __restrict__ bm,           // (P, BM_WORDS)
    const u16t* __restrict__ fwb,          // (N,48) bf16
    float* __restrict__ gacc,              // (P,44)
    u32t* __restrict__ done,
    const float* __restrict__ bc,          // (21)
    const float* __restrict__ bo,          // (21)
    float* __restrict__ out)               // (P,21)
{
    const int bid = blockIdx.x;
    const int x = bid & 7;
    const int p = (bid >> 3) & (P_PROP - 1);
    const int q = bid >> 11;               // 0..1

    const int t = threadIdx.x;
    const int wave = t >> 6;
    const int lane = t & 63;

    __shared__ int list[LIST_MAX];
    __shared__ float red[4][48];
    __shared__ u64t wbuf[SEG_WORDS];
    __shared__ int cnt;
    __shared__ int isLast;

    float sx = 0.0f, sy = 0.0f;
    int mtot = 0;

#pragma unroll 1
    for (int h = 0; h < 2; ++h) {
        const int s = q * 16 + h * 8 + x;

        if (t == 0) cnt = 0;
        if (t < SEG_WORDS) wbuf[t] = bm[(size_t)p * BM_WORDS + s * SEG_WORDS + t];
        __syncthreads();

        // ---- compact: 196 threads x one 16-bit chunk each ----
        if (t < SEG_WORDS * 4) {
            const int w  = t >> 2;
            const int sh = (t & 3) * 16;
            u32t bits = (u32t)((wbuf[w] >> sh) & 0xffffull);
            if (bits) {
                int base = atomicAdd(&cnt, __popc(bits));
                const int ibase = s * SEG_LEN + w * 64 + sh;
                while (bits) {
                    const int b = __ffs(bits) - 1;
                    list[base++] = ibase + b;
                    bits &= bits - 1;
                }
            }
        }
        __syncthreads();

        const int m = cnt;
        mtot += m;

        // ---- gather: lane = dword-channel pair, wave-strided rows ----
        if (lane < FW_STRIDE / 2) {
            const u32t* __restrict__ fw32 = (const u32t*)fwb;
            int j = wave;
            for (; j + 28 < m; j += 32) {
                int r[8];
#pragma unroll
                for (int u = 0; u < 8; ++u) r[u] = list[j + 4 * u];
                u32t f[8];
#pragma unroll
                for (int u = 0; u < 8; ++u)
                    f[u] = fw32[(size_t)r[u] * (FW_STRIDE / 2) + lane];
#pragma unroll
                for (int u = 0; u < 8; ++u) {
                    sx += __uint_as_float(f[u] << 16);
                    sy += __uint_as_float(f[u] & 0xffff0000u);
                }
            }
            for (; j < m; j += 4) {
                const u32t f = fw32[(size_t)list[j] * (FW_STRIDE / 2) + lane];
                sx += __uint_as_float(f << 16);
                sy += __uint_as_float(f & 0xffff0000u);
            }
        }
        __syncthreads();   // protect list/wbuf before next segment overwrites
    }

    if (lane < FW_STRIDE / 2 && wave < 4) {
        red[wave][lane * 2]     = sx;
        red[wave][lane * 2 + 1] = sy;
    }
    __syncthreads();

    if (t < 2 * NCLS) {
        const float v = red[0][t] + red[1][t] + red[2][t] + red[3][t];
        atomicAdd(&gacc[p * ACC_STRIDE + t], v);
    }
    if (t == 2 * NCLS) {
        atomicAdd(&gacc[p * ACC_STRIDE + 42], (float)mtot);
    }
    __syncthreads();

    // ---- last-block-done election ----
    if (t == 0) {
        __threadfence();
        const u32t prev = atomicAdd(done, 1u);
        isLast = (prev == ROI_BLOCKS - 1) ? 1 : 0;
    }
    __syncthreads();
    if (!isLast) return;

    // ================= fused softmax (last block only) =================
    __shared__ float objl[P_PROP][NCLS];
    __shared__ float red8[8][32];
    __shared__ float colmax[32];
    __shared__ float colsum[32];

    const int cc = t & 31;
    const int g = t >> 5;

    float v[ACC_STRIDE];
#pragma unroll
    for (int j = 0; j < ACC_STRIDE; ++j) {
        const u32t raw = __hip_atomic_load((const u32t*)&gacc[t * ACC_STRIDE + j],
                                           __ATOMIC_RELAXED, __HIP_MEMORY_SCOPE_AGENT);
        v[j] = __uint_as_float(raw);
    }

    const float cntv = fmaxf(v[42], 1.0f);
    const float rinv = 1.0f / cntv;

    float cl[NCLS], ob[NCLS];
#pragma unroll
    for (int c = 0; c < NCLS; ++c) {
        cl[c] = v[c] * rinv + bc[c];
        ob[c] = v[NCLS + c] * rinv + bo[c];
        objl[t][c] = ob[c];
    }
    __syncthreads();

    float m = -INFINITY;
    if (cc < NCLS) {
        const int p0 = g * 32;
        for (int pp = p0; pp < p0 + 32; ++pp) m = fmaxf(m, objl[pp][cc]);
    }
    red8[g][cc] = m;
    __syncthreads();
    if (t < NCLS) {
        float mm = red8[0][t];
#pragma unroll
        for (int gg = 1; gg < 8; ++gg) mm = fmaxf(mm, red8[gg][t]);
        colmax[t] = mm;
    }
    __syncthreads();

    float sc = 0.0f;
    if (cc < NCLS) {
        const float mm = colmax[cc];
        const int p0 = g * 32;
        for (int pp = p0; pp < p0 + 32; ++pp) sc += expf(objl[pp][cc] - mm);
    }
    red8[g][cc] = sc;
    __syncthreads();
    if (t < NCLS) {
        float ss = red8[0][t];
#pragma unroll
        for (int gg = 1; gg < 8; ++gg) ss += red8[gg][t];
        colsum[t] = ss;
    }

    float rm = cl[0];
#pragma unroll
    for (int c = 1; c < NCLS; ++c) rm = fmaxf(rm, cl[c]);
    float e[NCLS];
    float rs = 0.0f;
#pragma unroll
    for (int c = 0; c < NCLS; ++c) { e[c] = expf(cl[c] - rm); rs += e[c]; }
    const float inv = 1.0f / rs;

    __syncthreads();

#pragma unroll
    for (int c = 0; c < NCLS; ++c) {
        const float cp = e[c] * inv;
        const float op = expf(ob[c] - colmax[c]) / colsum[c];
        out[t * NCLS + c] = cp * op;
    }
}

// ---------------- launch ----------------------------------------------------
extern "C" void kernel_launch(void* const* d_in, const int* in_sizes, int n_in,
                              void* d_out, int out_size, void* d_ws, size_t ws_size,
                              hipStream_t stream) {
    const float* proposals = (const float*)d_in[0];  // (256,6)
    const float* xyz       = (const float*)d_in[1];  // (100000,3)
    const float* feats     = (const float*)d_in[2];  // (100000,256)
    const float* Wc        = (const float*)d_in[3];  // (256,21)
    const float* bc        = (const float*)d_in[4];  // (21)
    const float* Wo        = (const float*)d_in[5];  // (256,21)
    const float* bo        = (const float*)d_in[6];  // (21)
    float* out = (float*)d_out;                      // (256,21)

    char* ws = (char*)d_ws;
    u16t* fwb   = (u16t*)(ws);                            // 100000*48*2 = 9,600,000 B
    float* gacc = (float*)(ws + 9600000);                 // 256*44*4    = 45,056 B
    u64t* bm    = (u64t*)(ws + 9600000 + 45056);          // 256*1568*8  = 3,211,264 B
    u32t* done  = (u32t*)(ws + 9600000 + 45056 + 3211264);// 4 B

    featw_mask_kernel<<<FEATW_BLOCKS + MASK_BLOCKS, 256, 0, stream>>>(
        proposals, xyz, feats, Wc, Wo, fwb, gacc, bm, done);
    roi_softmax_kernel<<<ROI_BLOCKS, 256, 0, stream>>>(
        bm, fwb, gacc, done, bc, bo, out);
}

// Round 6
// 242.322 us; speedup vs baseline: 1.2922x; 1.2922x over previous
//
#include <hip/hip_runtime.h>
#include <math.h>

#define N_PTS 100000
#define P_PROP 256
#define R_FEAT 256
#define NCLS 21          // C + 1
#define NSEG 32          // segments of 3136 points
#define SEG_LEN 3136     // 64-aligned; NSEG*SEG_LEN = 100352 (pad bits/values = 0)
#define NP 100352        // padded point count = fwT row stride
#define SEG_WORDS (SEG_LEN / 64)            // 49
#define BM_WORDS (NSEG * SEG_WORDS)         // 1568 u64 words per proposal
#define ACC_STRIDE 44    // 42 channel sums + 1 count + 1 pad
#define MTILE 128        // rows per featw block (4 waves x 2 x 16-row MFMA tiles)
#define FEATW_BLOCKS ((N_PTS + MTILE - 1) / MTILE)   // 782 (covers 100096 rows)
#define NFRAG (3 * 8 * 64)   // B fragments: 3 N-tiles x 8 K-steps x 64 lanes
#define MASK_BLOCKS (NSEG * SEG_LEN / 256)  // 392
#define ROIB_BLOCKS 512      // 32 segments x 16 proposal-tiles

typedef unsigned short u16t;
typedef unsigned int u32t;
typedef unsigned long long u64t;
typedef __attribute__((ext_vector_type(8))) short short8;   // 8 bf16 (4 VGPRs)
typedef __attribute__((ext_vector_type(4))) float f32x4;    // MFMA accumulator

__device__ __forceinline__ u16t f2bf_rne(float x) {
    u32t u = __float_as_uint(x);
    u += 0x7fffu + ((u >> 16) & 1u);
    return (u16t)(u >> 16);
}

// ---------------- Kernel A: featw (MFMA, transposed out) + mask bitmap -----
// One launch, 1174 blocks. Blocks [0,782): fwT = (feats @ [Wc|Wo|pad])^T via
// mfma_f32_16x16x32_bf16, stored CHANNEL-major fwT[48][NP] so kernel B's
// A-fragments are contiguous b128 loads (round-5 lesson: the row-gather
// structure was a 119us latency chain; dense MFMA needs transposed layout).
// Blocks [782,1174): dense mask bitmap (one u64 ballot per proposal per
// 64-point wave); first mask block also zeroes gacc, done, and fwT's pad
// columns [100000,100352) so pad contributes exactly 0 in kernel B.
__global__ __launch_bounds__(256) void featw_mask_kernel(
    const float* __restrict__ proposals,   // (P,6)
    const float* __restrict__ xyz,         // (N,3)
    const float* __restrict__ feats,       // (N,R)
    const float* __restrict__ Wc,          // (R,21)
    const float* __restrict__ Wo,          // (R,21)
    u16t* __restrict__ fwT,                // (48, NP) bf16, channel-major
    float* __restrict__ gacc,              // (P,44) zeroed here
    u64t* __restrict__ bm,                 // (P, BM_WORDS)
    u32t* __restrict__ done)               // zeroed here
{
    const int t = threadIdx.x;

    if (blockIdx.x < FEATW_BLOCKS) {
        // ================= featw role =================
        __shared__ u16t bB[NFRAG * 8];     // 24 KiB of pre-swizzled B-frags

        for (int idx = t; idx < NFRAG; idx += 256) {
            const int n   = idx >> 9;         // N-tile 0..2
            const int rem = idx & 511;
            const int kk  = rem >> 6;         // K-step 0..7
            const int l   = rem & 63;         // lane
            const int krow = kk * 32 + (l >> 4) * 8;
            const int c    = n * 16 + (l & 15);
            u32t w[4];
#pragma unroll
            for (int jj = 0; jj < 4; ++jj) {
                const int k0 = krow + 2 * jj;
                float v0 = 0.0f, v1 = 0.0f;
                if (c < NCLS) {
                    v0 = Wc[k0 * NCLS + c];
                    v1 = Wc[(k0 + 1) * NCLS + c];
                } else if (c < 2 * NCLS) {
                    v0 = Wo[k0 * NCLS + (c - NCLS)];
                    v1 = Wo[(k0 + 1) * NCLS + (c - NCLS)];
                }
                w[jj] = (u32t)f2bf_rne(v0) | ((u32t)f2bf_rne(v1) << 16);
            }
            *(uint4*)(&bB[idx * 8]) = make_uint4(w[0], w[1], w[2], w[3]);
        }
        __syncthreads();

        const int wv = t >> 6;
        const int l  = t & 63;
        const int rowbase = blockIdx.x * MTILE + wv * 32;

        const int r0 = rowbase + (l & 15);
        const int r1 = r0 + 16;
        const int r0c = r0 < N_PTS ? r0 : N_PTS - 1;
        const int r1c = r1 < N_PTS ? r1 : N_PTS - 1;
        const float* __restrict__ a0p = feats + (size_t)r0c * R_FEAT + (l >> 4) * 8;
        const float* __restrict__ a1p = feats + (size_t)r1c * R_FEAT + (l >> 4) * 8;

        f32x4 c00 = {0.f,0.f,0.f,0.f}, c01 = {0.f,0.f,0.f,0.f}, c02 = {0.f,0.f,0.f,0.f};
        f32x4 c10 = {0.f,0.f,0.f,0.f}, c11 = {0.f,0.f,0.f,0.f}, c12 = {0.f,0.f,0.f,0.f};

#pragma unroll
        for (int kk = 0; kk < 8; ++kk) {
            const short8 b0 = *(const short8*)(&bB[((0 * 8 + kk) * 64 + l) * 8]);
            const short8 b1 = *(const short8*)(&bB[((1 * 8 + kk) * 64 + l) * 8]);
            const short8 b2 = *(const short8*)(&bB[((2 * 8 + kk) * 64 + l) * 8]);

            const float4 x0 = *(const float4*)(a0p + kk * 32);
            const float4 x1 = *(const float4*)(a0p + kk * 32 + 4);
            union { u32t u[4]; short8 s; } af0;
            af0.u[0] = (u32t)f2bf_rne(x0.x) | ((u32t)f2bf_rne(x0.y) << 16);
            af0.u[1] = (u32t)f2bf_rne(x0.z) | ((u32t)f2bf_rne(x0.w) << 16);
            af0.u[2] = (u32t)f2bf_rne(x1.x) | ((u32t)f2bf_rne(x1.y) << 16);
            af0.u[3] = (u32t)f2bf_rne(x1.z) | ((u32t)f2bf_rne(x1.w) << 16);
            c00 = __builtin_amdgcn_mfma_f32_16x16x32_bf16(af0.s, b0, c00, 0, 0, 0);
            c01 = __builtin_amdgcn_mfma_f32_16x16x32_bf16(af0.s, b1, c01, 0, 0, 0);
            c02 = __builtin_amdgcn_mfma_f32_16x16x32_bf16(af0.s, b2, c02, 0, 0, 0);

            const float4 y0 = *(const float4*)(a1p + kk * 32);
            const float4 y1 = *(const float4*)(a1p + kk * 32 + 4);
            union { u32t u[4]; short8 s; } af1;
            af1.u[0] = (u32t)f2bf_rne(y0.x) | ((u32t)f2bf_rne(y0.y) << 16);
            af1.u[1] = (u32t)f2bf_rne(y0.z) | ((u32t)f2bf_rne(y0.w) << 16);
            af1.u[2] = (u32t)f2bf_rne(y1.x) | ((u32t)f2bf_rne(y1.y) << 16);
            af1.u[3] = (u32t)f2bf_rne(y1.z) | ((u32t)f2bf_rne(y1.w) << 16);
            c10 = __builtin_amdgcn_mfma_f32_16x16x32_bf16(af1.s, b0, c10, 0, 0, 0);
            c11 = __builtin_amdgcn_mfma_f32_16x16x32_bf16(af1.s, b1, c11, 0, 0, 0);
            c12 = __builtin_amdgcn_mfma_f32_16x16x32_bf16(af1.s, b2, c12, 0, 0, 0);
        }

        // ---- transposed epilogue: D col = lane&15 = channel, rows = 4 pts.
        // fwT[ch][pt]: 4 consecutive bf16 -> one 8B write (or0 % 4 == 0).
        const int ch  = l & 15;
        const int or0 = rowbase + (l >> 4) * 4;
        if (or0 + 3 < N_PTS) {
            *(uint2*)(fwT + (size_t)ch * NP + or0) = make_uint2(
                (u32t)f2bf_rne(c00[0]) | ((u32t)f2bf_rne(c00[1]) << 16),
                (u32t)f2bf_rne(c00[2]) | ((u32t)f2bf_rne(c00[3]) << 16));
            *(uint2*)(fwT + (size_t)(ch + 16) * NP + or0) = make_uint2(
                (u32t)f2bf_rne(c01[0]) | ((u32t)f2bf_rne(c01[1]) << 16),
                (u32t)f2bf_rne(c01[2]) | ((u32t)f2bf_rne(c01[3]) << 16));
            *(uint2*)(fwT + (size_t)(ch + 32) * NP + or0) = make_uint2(
                (u32t)f2bf_rne(c02[0]) | ((u32t)f2bf_rne(c02[1]) << 16),
                (u32t)f2bf_rne(c02[2]) | ((u32t)f2bf_rne(c02[3]) << 16));
        }
        const int or1 = or0 + 16;
        if (or1 + 3 < N_PTS) {
            *(uint2*)(fwT + (size_t)ch * NP + or1) = make_uint2(
                (u32t)f2bf_rne(c10[0]) | ((u32t)f2bf_rne(c10[1]) << 16),
                (u32t)f2bf_rne(c10[2]) | ((u32t)f2bf_rne(c10[3]) << 16));
            *(uint2*)(fwT + (size_t)(ch + 16) * NP + or1) = make_uint2(
                (u32t)f2bf_rne(c11[0]) | ((u32t)f2bf_rne(c11[1]) << 16),
                (u32t)f2bf_rne(c11[2]) | ((u32t)f2bf_rne(c11[3]) << 16));
            *(uint2*)(fwT + (size_t)(ch + 32) * NP + or1) = make_uint2(
                (u32t)f2bf_rne(c12[0]) | ((u32t)f2bf_rne(c12[1]) << 16),
                (u32t)f2bf_rne(c12[2]) | ((u32t)f2bf_rne(c12[3]) << 16));
        }
        return;
    }

    // ================= mask role =================
    const int mb = blockIdx.x - FEATW_BLOCKS;   // 0..391
    if (mb == 0) {
        for (int i = t; i < P_PROP * ACC_STRIDE; i += 256) gacc[i] = 0.0f;
        if (t == 0) *done = 0u;
        // zero fwT pad columns [N_PTS, NP) for all 48 channels (176 u32/row)
        for (int i = t; i < 48 * 176; i += 256) {
            const int chn = i / 176;
            const int o   = i - chn * 176;
            *(u32t*)(fwT + (size_t)chn * NP + N_PTS + o * 2) = 0u;
        }
    }

    __shared__ float4 plohi[P_PROP][2];    // [0]=lox,loy,loz,hix  [1]=hiy,hiz,-,-
    for (int pp = t; pp < P_PROP; pp += 256) {
        const float cx = proposals[pp * 6 + 0];
        const float cy = proposals[pp * 6 + 1];
        const float cz = proposals[pp * 6 + 2];
        const float hx = proposals[pp * 6 + 3] * 0.5f;
        const float hy = proposals[pp * 6 + 4] * 0.5f;
        const float hz = proposals[pp * 6 + 5] * 0.5f;
        plohi[pp][0] = make_float4(cx - hx, cy - hy, cz - hz, cx + hx);
        plohi[pp][1] = make_float4(cy + hy, cz + hz, 0.0f, 0.0f);
    }
    __syncthreads();

    const int i = mb * 256 + t;
    const bool alive = i < N_PTS;
    const int ic = alive ? i : 0;
    const float xx = xyz[ic * 3 + 0];
    const float yy = xyz[ic * 3 + 1];
    const float zz = xyz[ic * 3 + 2];
    const int lane = t & 63;
    const int iw = mb * 4 + (t >> 6);      // global u64 word index for this wave

#pragma unroll 8
    for (int p = 0; p < P_PROP; ++p) {
        const float4 a = plohi[p][0];
        const float4 b = plohi[p][1];
        const bool in = alive &
                        (xx >= a.x) & (xx <= a.w) &
                        (yy >= a.y) & (yy <= b.x) &
                        (zz >= a.z) & (zz <= b.y);
        const u64t msk = __ballot(in);
        if (lane == 0) bm[(size_t)p * BM_WORDS + iw] = msk;
    }
}

// ---------------- Kernel B: ROI-sum as MFMA + atomic combine + softmax -----
// roisum[p][c] = sum_i mask[p][i]*fW[i][c] = mask @ fW: computed as
// fwT-tile (A: 16ch x 32pt, contiguous b128 loads) x mask-frag (B: 32pt x
// 16props, synthesized IN REGISTERS from the bitmap -- 0/1 exact in bf16).
// grid = 512 = 32 seg x 16 ptile, swizzled so each XCD holds 4 segment
// windows (4 x 301KB, L2-resident) reused by 16 ptile blocks. No list, no
// compaction, no gather (round-5 lesson: that chain was 119us latency-bound).
// Counts via popcount of the staged bitmap. Last-done block runs the proven
// softmax, reading gacc with agent-scope atomic loads (G16).
__global__ __launch_bounds__(256) void mfma_sum_softmax_kernel(
    const u64t* __restrict__ bm,           // (P, BM_WORDS)
    const u16t* __restrict__ fwT,          // (48, NP) bf16
    float* __restrict__ gacc,              // (P,44)
    u32t* __restrict__ done,
    const float* __restrict__ bc,          // (21)
    const float* __restrict__ bo,          // (21)
    float* __restrict__ out)               // (P,21)
{
    const int bid   = blockIdx.x;
    const int seg   = (bid & 7) + 8 * (bid >> 7);   // XCD = seg%8
    const int ptile = (bid >> 3) & 15;
    const int p0    = ptile * 16;

    const int t  = threadIdx.x;
    const int wv = t >> 6;
    const int l  = t & 63;

    __shared__ union {
        struct {                            // MFMA phase
            u64t  mwin[16][SEG_WORDS];      // 6272 B
            float red[4][3][16][16];        // 12288 B
        } a;
        struct {                            // softmax phase (barrier-separated)
            float objl[P_PROP][NCLS];       // 21504 B
            float red8[8][32];
            float colmax[32];
            float colsum[32];
        } b;
    } sh;
    __shared__ int isLast;

    // ---- stage this block's bitmap window: 16 proposals x 49 u64 ----
    for (int i = t; i < 16 * SEG_WORDS; i += 256) {
        const int pi = i / SEG_WORDS;
        const int w  = i - pi * SEG_WORDS;
        sh.a.mwin[pi][w] = bm[(size_t)(p0 + pi) * BM_WORDS + seg * SEG_WORDS + w];
    }
    __syncthreads();

    // ---- MFMA K-loop: 98 k-steps of 32 points split 25/25/24/24 ----
    const int ks0 = wv * 24 + (wv < 2 ? wv : 2);
    const int ks1 = ks0 + (wv < 2 ? 25 : 24);

    const int ch = l & 15;                 // A row (channel within tile)
    const int kg = l >> 4;                 // k-group 0..3
    const u16t* __restrict__ aBase =
        fwT + (size_t)ch * NP + (size_t)seg * SEG_LEN + kg * 8;

    f32x4 acc0 = {0.f,0.f,0.f,0.f};
    f32x4 acc1 = {0.f,0.f,0.f,0.f};
    f32x4 acc2 = {0.f,0.f,0.f,0.f};

#pragma unroll 1
    for (int ks = ks0; ks < ks1; ++ks) {
        const int off = ks * 32;
        const short8 a0 = *(const short8*)(aBase + off);
        const short8 a1 = *(const short8*)(aBase + (size_t)16 * NP + off);
        const short8 a2 = *(const short8*)(aBase + (size_t)32 * NP + off);

        // B-frag: col = l&15 = proposal, k = kg*8+j -> 8 bitmap bits
        const int lp0 = off + kg * 8;
        const u32t bits8 =
            (u32t)((sh.a.mwin[l & 15][lp0 >> 6] >> (lp0 & 63)) & 0xFFull);
        union { u32t u[4]; short8 s; } bb;
#pragma unroll
        for (int jj = 0; jj < 4; ++jj)
            bb.u[jj] = (((bits8 >> (2 * jj)) & 1u) ? 0x3F80u : 0u) |
                       (((bits8 >> (2 * jj + 1)) & 1u) ? 0x3F800000u : 0u);

        acc0 = __builtin_amdgcn_mfma_f32_16x16x32_bf16(a0, bb.s, acc0, 0, 0, 0);
        acc1 = __builtin_amdgcn_mfma_f32_16x16x32_bf16(a1, bb.s, acc1, 0, 0, 0);
        acc2 = __builtin_amdgcn_mfma_f32_16x16x32_bf16(a2, bb.s, acc2, 0, 0, 0);
    }

    // ---- cross-wave reduce: D col = l&15 = proposal, row = kg*4+j = ch ----
#pragma unroll
    for (int j = 0; j < 4; ++j) {
        sh.a.red[wv][0][kg * 4 + j][l & 15] = acc0[j];
        sh.a.red[wv][1][kg * 4 + j][l & 15] = acc1[j];
        sh.a.red[wv][2][kg * 4 + j][l & 15] = acc2[j];
    }
    __syncthreads();

    for (int i = t; i < 768; i += 256) {
        const int ct  = i >> 8;
        const int rem = i & 255;
        const int row = rem >> 4;
        const int col = rem & 15;
        const int chg = ct * 16 + row;
        if (chg < 2 * NCLS) {
            const float v = sh.a.red[0][ct][row][col] + sh.a.red[1][ct][row][col] +
                            sh.a.red[2][ct][row][col] + sh.a.red[3][ct][row][col];
            atomicAdd(&gacc[(p0 + col) * ACC_STRIDE + chg], v);
        }
    }
    if (t < 16) {
        int c = 0;
#pragma unroll 1
        for (int w = 0; w < SEG_WORDS; ++w) c += __popcll(sh.a.mwin[t][w]);
        atomicAdd(&gacc[(p0 + t) * ACC_STRIDE + 42], (float)c);
    }
    __syncthreads();

    // ---- last-block-done election ----
    if (t == 0) {
        __threadfence();
        const u32t prev = atomicAdd(done, 1u);
        isLast = (prev == ROIB_BLOCKS - 1) ? 1 : 0;
    }
    __syncthreads();
    if (!isLast) return;

    // ================= fused softmax (last block only) =================
    const int cc = t & 31;
    const int g = t >> 5;

    float v[ACC_STRIDE];
#pragma unroll
    for (int j = 0; j < ACC_STRIDE; ++j) {
        const u32t raw = __hip_atomic_load((const u32t*)&gacc[t * ACC_STRIDE + j],
                                           __ATOMIC_RELAXED, __HIP_MEMORY_SCOPE_AGENT);
        v[j] = __uint_as_float(raw);
    }

    const float cntv = fmaxf(v[42], 1.0f);
    const float rinv = 1.0f / cntv;

    float cl[NCLS], ob[NCLS];
#pragma unroll
    for (int c = 0; c < NCLS; ++c) {
        cl[c] = v[c] * rinv + bc[c];
        ob[c] = v[NCLS + c] * rinv + bo[c];
        sh.b.objl[t][c] = ob[c];
    }
    __syncthreads();

    float m = -INFINITY;
    if (cc < NCLS) {
        const int q0 = g * 32;
        for (int pp = q0; pp < q0 + 32; ++pp) m = fmaxf(m, sh.b.objl[pp][cc]);
    }
    sh.b.red8[g][cc] = m;
    __syncthreads();
    if (t < NCLS) {
        float mm = sh.b.red8[0][t];
#pragma unroll
        for (int gg = 1; gg < 8; ++gg) mm = fmaxf(mm, sh.b.red8[gg][t]);
        sh.b.colmax[t] = mm;
    }
    __syncthreads();

    float sc = 0.0f;
    if (cc < NCLS) {
        const float mm = sh.b.colmax[cc];
        const int q0 = g * 32;
        for (int pp = q0; pp < q0 + 32; ++pp) sc += expf(sh.b.objl[pp][cc] - mm);
    }
    sh.b.red8[g][cc] = sc;
    __syncthreads();
    if (t < NCLS) {
        float ss = sh.b.red8[0][t];
#pragma unroll
        for (int gg = 1; gg < 8; ++gg) ss += sh.b.red8[gg][t];
        sh.b.colsum[t] = ss;
    }

    float rm = cl[0];
#pragma unroll
    for (int c = 1; c < NCLS; ++c) rm = fmaxf(rm, cl[c]);
    float e[NCLS];
    float rs = 0.0f;
#pragma unroll
    for (int c = 0; c < NCLS; ++c) { e[c] = expf(cl[c] - rm); rs += e[c]; }
    const float inv = 1.0f / rs;

    __syncthreads();

#pragma unroll
    for (int c = 0; c < NCLS; ++c) {
        const float cp = e[c] * inv;
        const float op = expf(ob[c] - sh.b.colmax[c]) / sh.b.colsum[c];
        out[t * NCLS + c] = cp * op;
    }
}

// ---------------- launch ----------------------------------------------------
extern "C" void kernel_launch(void* const* d_in, const int* in_sizes, int n_in,
                              void* d_out, int out_size, void* d_ws, size_t ws_size,
                              hipStream_t stream) {
    const float* proposals = (const float*)d_in[0];  // (256,6)
    const float* xyz       = (const float*)d_in[1];  // (100000,3)
    const float* feats     = (const float*)d_in[2];  // (100000,256)
    const float* Wc        = (const float*)d_in[3];  // (256,21)
    const float* bc        = (const float*)d_in[4];  // (21)
    const float* Wo        = (const float*)d_in[5];  // (256,21)
    const float* bo        = (const float*)d_in[6];  // (21)
    float* out = (float*)d_out;                      // (256,21)

    char* ws = (char*)d_ws;
    u16t* fwT   = (u16t*)(ws);                             // 48*100352*2 = 9,633,792 B
    float* gacc = (float*)(ws + 9633792);                  // 256*44*4    = 45,056 B
    u64t* bm    = (u64t*)(ws + 9633792 + 45056);           // 256*1568*8  = 3,211,264 B
    u32t* done  = (u32t*)(ws + 9633792 + 45056 + 3211264); // 4 B

    featw_mask_kernel<<<FEATW_BLOCKS + MASK_BLOCKS, 256, 0, stream>>>(
        proposals, xyz, feats, Wc, Wo, fwT, gacc, bm, done);
    mfma_sum_softmax_kernel<<<ROIB_BLOCKS, 256, 0, stream>>>(
        bm, fwT, gacc, done, bc, bo, out);
}

// Round 7
// 240.354 us; speedup vs baseline: 1.3028x; 1.0082x over previous
//
#include <hip/hip_runtime.h>
#include <math.h>

#define N_PTS 100000
#define P_PROP 256
#define R_FEAT 256
#define NCLS 21          // C + 1
#define NSEG 32          // segments of 3136 points
#define SEG_LEN 3136     // 64-aligned; NSEG*SEG_LEN = 100352 (pad bits/values = 0)
#define NP 100352        // padded point count = fwT row stride
#define SEG_WORDS (SEG_LEN / 64)            // 49
#define BM_WORDS (NSEG * SEG_WORDS)         // 1568 u64 words per proposal
#define ACC_STRIDE 44    // 42 channel sums + 1 count + 1 pad
#define MTILE 128        // rows per featw block (4 waves x 2 x 16-row MFMA tiles)
#define FEATW_BLOCKS ((N_PTS + MTILE - 1) / MTILE)   // 782 (covers 100096 rows)
#define NFRAG (3 * 8 * 64)   // B fragments: 3 N-tiles x 8 K-steps x 64 lanes
#define MASK_BLOCKS (NSEG * SEG_LEN / 256)  // 392
#define ROIB_BLOCKS 512      // 32 segments x 16 proposal-tiles
#define PREP_BLOCKS 8

typedef unsigned short u16t;
typedef unsigned int u32t;
typedef unsigned long long u64t;
typedef __attribute__((ext_vector_type(8))) short short8;   // 8 bf16 (4 VGPRs)
typedef __attribute__((ext_vector_type(4))) float f32x4;    // MFMA accumulator

__device__ __forceinline__ u16t f2bf_rne(float x) {
    u32t u = __float_as_uint(x);
    u += 0x7fffu + ((u >> 16) & 1u);
    return (u16t)(u >> 16);
}

// ---------------- Kernel P: B-frag image + zero gacc/done/fwT-pad ----------
// 8 blocks, grid-stride. Round-6 lesson: the in-block B-frag build (4.8M
// scattered dword loads across 782 blocks) plus VGPR=48 plus 32KB LDS made
// featw latency-bound at 82us. The image is built ONCE here; featw copies
// it with 6 coalesced uint4 loads per thread.
__global__ __launch_bounds__(256) void prep_kernel(
    const float* __restrict__ Wc,      // (R,21)
    const float* __restrict__ Wo,      // (R,21)
    u16t* __restrict__ bfragG,         // (NFRAG*8) bf16 = 24576 B
    float* __restrict__ gacc,          // (P,44) zeroed
    u16t* __restrict__ fwT,            // pad columns [N_PTS,NP) zeroed
    u32t* __restrict__ done)           // zeroed
{
    const int g0 = blockIdx.x * 256 + threadIdx.x;
    const int gs = PREP_BLOCKS * 256;

    if (g0 == 0) *done = 0u;
    for (int i = g0; i < P_PROP * ACC_STRIDE; i += gs) gacc[i] = 0.0f;
    for (int i = g0; i < 48 * 176; i += gs) {         // 352 pad pts x 48 ch (u32 pairs)
        const int chn = i / 176;
        const int o   = i - chn * 176;
        *(u32t*)(fwT + (size_t)chn * NP + N_PTS + o * 2) = 0u;
    }

    for (int idx = g0; idx < NFRAG; idx += gs) {
        const int n   = idx >> 9;         // N-tile 0..2
        const int rem = idx & 511;
        const int kk  = rem >> 6;         // K-step 0..7
        const int l   = rem & 63;         // lane
        const int krow = kk * 32 + (l >> 4) * 8;
        const int c    = n * 16 + (l & 15);
        u32t w[4];
#pragma unroll
        for (int jj = 0; jj < 4; ++jj) {
            const int k0 = krow + 2 * jj;
            float v0 = 0.0f, v1 = 0.0f;
            if (c < NCLS) {
                v0 = Wc[k0 * NCLS + c];
                v1 = Wc[(k0 + 1) * NCLS + c];
            } else if (c < 2 * NCLS) {
                v0 = Wo[k0 * NCLS + (c - NCLS)];
                v1 = Wo[(k0 + 1) * NCLS + (c - NCLS)];
            }
            w[jj] = (u32t)f2bf_rne(v0) | ((u32t)f2bf_rne(v1) << 16);
        }
        *(uint4*)(&bfragG[idx * 8]) = make_uint4(w[0], w[1], w[2], w[3]);
    }
}

// ---------------- Kernel A: featw (MFMA, transposed out) + mask bitmap -----
// 1174 blocks. Blocks [0,782): fwT = (feats @ [Wc|Wo|pad])^T via
// mfma_f32_16x16x32_bf16; B-frags are a coalesced copy of the prep image;
// K-loop software-pipelined (next k-step's 4 float4 prefetched in registers).
// __launch_bounds__(256,3) lifts the round-6 VGPR=48 cap so the prefetch
// actually stays in flight. Blocks [782,1174): dense mask bitmap. LDS: bB
// and plohi UNIONed (round-6 bug: both allocated -> 32KB -> 5 blocks/CU).
__global__ __launch_bounds__(256, 3) void featw_mask_kernel(
    const float* __restrict__ proposals,   // (P,6)
    const float* __restrict__ xyz,         // (N,3)
    const float* __restrict__ feats,       // (N,R)
    const u16t* __restrict__ bfragG,       // prep image
    u16t* __restrict__ fwT,                // (48, NP) bf16, channel-major
    u64t* __restrict__ bm)                 // (P, BM_WORDS)
{
    const int t = threadIdx.x;

    __shared__ union {
        u16t   bB[NFRAG * 8];              // featw role: 24576 B
        float4 plohi[P_PROP][2];           // mask role:   8192 B
    } sh;

    if (blockIdx.x < FEATW_BLOCKS) {
        // ================= featw role =================
#pragma unroll
        for (int i = 0; i < 6; ++i)
            ((uint4*)sh.bB)[t + i * 256] = ((const uint4*)bfragG)[t + i * 256];
        __syncthreads();

        const int wv = t >> 6;
        const int l  = t & 63;
        const int rowbase = blockIdx.x * MTILE + wv * 32;

        const int r0 = rowbase + (l & 15);
        const int r1 = r0 + 16;
        const int r0c = r0 < N_PTS ? r0 : N_PTS - 1;
        const int r1c = r1 < N_PTS ? r1 : N_PTS - 1;
        const float* __restrict__ a0p = feats + (size_t)r0c * R_FEAT + (l >> 4) * 8;
        const float* __restrict__ a1p = feats + (size_t)r1c * R_FEAT + (l >> 4) * 8;

        f32x4 c00 = {0.f,0.f,0.f,0.f}, c01 = {0.f,0.f,0.f,0.f}, c02 = {0.f,0.f,0.f,0.f};
        f32x4 c10 = {0.f,0.f,0.f,0.f}, c11 = {0.f,0.f,0.f,0.f}, c12 = {0.f,0.f,0.f,0.f};

        float4 x0 = *(const float4*)(a0p);
        float4 x1 = *(const float4*)(a0p + 4);
        float4 y0 = *(const float4*)(a1p);
        float4 y1 = *(const float4*)(a1p + 4);

#pragma unroll
        for (int kk = 0; kk < 8; ++kk) {
            float4 nx0, nx1, ny0, ny1;
            if (kk < 7) {
                nx0 = *(const float4*)(a0p + (kk + 1) * 32);
                nx1 = *(const float4*)(a0p + (kk + 1) * 32 + 4);
                ny0 = *(const float4*)(a1p + (kk + 1) * 32);
                ny1 = *(const float4*)(a1p + (kk + 1) * 32 + 4);
            }

            const short8 b0 = *(const short8*)(&sh.bB[((0 * 8 + kk) * 64 + l) * 8]);
            const short8 b1 = *(const short8*)(&sh.bB[((1 * 8 + kk) * 64 + l) * 8]);
            const short8 b2 = *(const short8*)(&sh.bB[((2 * 8 + kk) * 64 + l) * 8]);

            union { u32t u[4]; short8 s; } af0;
            af0.u[0] = (u32t)f2bf_rne(x0.x) | ((u32t)f2bf_rne(x0.y) << 16);
            af0.u[1] = (u32t)f2bf_rne(x0.z) | ((u32t)f2bf_rne(x0.w) << 16);
            af0.u[2] = (u32t)f2bf_rne(x1.x) | ((u32t)f2bf_rne(x1.y) << 16);
            af0.u[3] = (u32t)f2bf_rne(x1.z) | ((u32t)f2bf_rne(x1.w) << 16);
            c00 = __builtin_amdgcn_mfma_f32_16x16x32_bf16(af0.s, b0, c00, 0, 0, 0);
            c01 = __builtin_amdgcn_mfma_f32_16x16x32_bf16(af0.s, b1, c01, 0, 0, 0);
            c02 = __builtin_amdgcn_mfma_f32_16x16x32_bf16(af0.s, b2, c02, 0, 0, 0);

            union { u32t u[4]; short8 s; } af1;
            af1.u[0] = (u32t)f2bf_rne(y0.x) | ((u32t)f2bf_rne(y0.y) << 16);
            af1.u[1] = (u32t)f2bf_rne(y0.z) | ((u32t)f2bf_rne(y0.w) << 16);
            af1.u[2] = (u32t)f2bf_rne(y1.x) | ((u32t)f2bf_rne(y1.y) << 16);
            af1.u[3] = (u32t)f2bf_rne(y1.z) | ((u32t)f2bf_rne(y1.w) << 16);
            c10 = __builtin_amdgcn_mfma_f32_16x16x32_bf16(af1.s, b0, c10, 0, 0, 0);
            c11 = __builtin_amdgcn_mfma_f32_16x16x32_bf16(af1.s, b1, c11, 0, 0, 0);
            c12 = __builtin_amdgcn_mfma_f32_16x16x32_bf16(af1.s, b2, c12, 0, 0, 0);

            if (kk < 7) { x0 = nx0; x1 = nx1; y0 = ny0; y1 = ny1; }
        }

        // ---- transposed epilogue: D col = lane&15 = channel, rows = 4 pts.
        const int ch  = l & 15;
        const int or0 = rowbase + (l >> 4) * 4;
        if (or0 + 3 < N_PTS) {
            *(uint2*)(fwT + (size_t)ch * NP + or0) = make_uint2(
                (u32t)f2bf_rne(c00[0]) | ((u32t)f2bf_rne(c00[1]) << 16),
                (u32t)f2bf_rne(c00[2]) | ((u32t)f2bf_rne(c00[3]) << 16));
            *(uint2*)(fwT + (size_t)(ch + 16) * NP + or0) = make_uint2(
                (u32t)f2bf_rne(c01[0]) | ((u32t)f2bf_rne(c01[1]) << 16),
                (u32t)f2bf_rne(c01[2]) | ((u32t)f2bf_rne(c01[3]) << 16));
            *(uint2*)(fwT + (size_t)(ch + 32) * NP + or0) = make_uint2(
                (u32t)f2bf_rne(c02[0]) | ((u32t)f2bf_rne(c02[1]) << 16),
                (u32t)f2bf_rne(c02[2]) | ((u32t)f2bf_rne(c02[3]) << 16));
        }
        const int or1 = or0 + 16;
        if (or1 + 3 < N_PTS) {
            *(uint2*)(fwT + (size_t)ch * NP + or1) = make_uint2(
                (u32t)f2bf_rne(c10[0]) | ((u32t)f2bf_rne(c10[1]) << 16),
                (u32t)f2bf_rne(c10[2]) | ((u32t)f2bf_rne(c10[3]) << 16));
            *(uint2*)(fwT + (size_t)(ch + 16) * NP + or1) = make_uint2(
                (u32t)f2bf_rne(c11[0]) | ((u32t)f2bf_rne(c11[1]) << 16),
                (u32t)f2bf_rne(c11[2]) | ((u32t)f2bf_rne(c11[3]) << 16));
            *(uint2*)(fwT + (size_t)(ch + 32) * NP + or1) = make_uint2(
                (u32t)f2bf_rne(c12[0]) | ((u32t)f2bf_rne(c12[1]) << 16),
                (u32t)f2bf_rne(c12[2]) | ((u32t)f2bf_rne(c12[3]) << 16));
        }
        return;
    }

    // ================= mask role =================
    const int mb = blockIdx.x - FEATW_BLOCKS;   // 0..391
    for (int pp = t; pp < P_PROP; pp += 256) {
        const float cx = proposals[pp * 6 + 0];
        const float cy = proposals[pp * 6 + 1];
        const float cz = proposals[pp * 6 + 2];
        const float hx = proposals[pp * 6 + 3] * 0.5f;
        const float hy = proposals[pp * 6 + 4] * 0.5f;
        const float hz = proposals[pp * 6 + 5] * 0.5f;
        sh.plohi[pp][0] = make_float4(cx - hx, cy - hy, cz - hz, cx + hx);
        sh.plohi[pp][1] = make_float4(cy + hy, cz + hz, 0.0f, 0.0f);
    }
    __syncthreads();

    const int i = mb * 256 + t;
    const bool alive = i < N_PTS;
    const int ic = alive ? i : 0;
    const float xx = xyz[ic * 3 + 0];
    const float yy = xyz[ic * 3 + 1];
    const float zz = xyz[ic * 3 + 2];
    const int lane = t & 63;
    const int iw = mb * 4 + (t >> 6);      // global u64 word index for this wave

#pragma unroll 8
    for (int p = 0; p < P_PROP; ++p) {
        const float4 a = sh.plohi[p][0];
        const float4 b = sh.plohi[p][1];
        const bool in = alive &
                        (xx >= a.x) & (xx <= a.w) &
                        (yy >= a.y) & (yy <= b.x) &
                        (zz >= a.z) & (zz <= b.y);
        const u64t msk = __ballot(in);
        if (lane == 0) bm[(size_t)p * BM_WORDS + iw] = msk;
    }
}

// ---------------- Kernel B: ROI-sum as MFMA + atomic combine + softmax -----
// Unchanged from round 6 (passed, off the top-5). roisum = mask @ fW with
// mask B-frags synthesized in registers from the bitmap; last-done block
// runs the softmax with agent-scope gacc loads (G16).
__global__ __launch_bounds__(256) void mfma_sum_softmax_kernel(
    const u64t* __restrict__ bm,           // (P, BM_WORDS)
    const u16t* __restrict__ fwT,          // (48, NP) bf16
    float* __restrict__ gacc,              // (P,44)
    u32t* __restrict__ done,
    const float* __restrict__ bc,          // (21)
    const float* __restrict__ bo,          // (21)
    float* __restrict__ out)               // (P,21)
{
    const int bid   = blockIdx.x;
    const int seg   = (bid & 7) + 8 * (bid >> 7);   // XCD = seg%8
    const int ptile = (bid >> 3) & 15;
    const int p0    = ptile * 16;

    const int t  = threadIdx.x;
    const int wv = t >> 6;
    const int l  = t & 63;

    __shared__ union {
        struct {                            // MFMA phase
            u64t  mwin[16][SEG_WORDS];      // 6272 B
            float red[4][3][16][16];        // 12288 B
        } a;
        struct {                            // softmax phase (barrier-separated)
            float objl[P_PROP][NCLS];       // 21504 B
            float red8[8][32];
            float colmax[32];
            float colsum[32];
        } b;
    } sh;
    __shared__ int isLast;

    // ---- stage this block's bitmap window: 16 proposals x 49 u64 ----
    for (int i = t; i < 16 * SEG_WORDS; i += 256) {
        const int pi = i / SEG_WORDS;
        const int w  = i - pi * SEG_WORDS;
        sh.a.mwin[pi][w] = bm[(size_t)(p0 + pi) * BM_WORDS + seg * SEG_WORDS + w];
    }
    __syncthreads();

    // ---- MFMA K-loop: 98 k-steps of 32 points split 25/25/24/24 ----
    const int ks0 = wv * 24 + (wv < 2 ? wv : 2);
    const int ks1 = ks0 + (wv < 2 ? 25 : 24);

    const int ch = l & 15;                 // A row (channel within tile)
    const int kg = l >> 4;                 // k-group 0..3
    const u16t* __restrict__ aBase =
        fwT + (size_t)ch * NP + (size_t)seg * SEG_LEN + kg * 8;

    f32x4 acc0 = {0.f,0.f,0.f,0.f};
    f32x4 acc1 = {0.f,0.f,0.f,0.f};
    f32x4 acc2 = {0.f,0.f,0.f,0.f};

#pragma unroll 1
    for (int ks = ks0; ks < ks1; ++ks) {
        const int off = ks * 32;
        const short8 a0 = *(const short8*)(aBase + off);
        const short8 a1 = *(const short8*)(aBase + (size_t)16 * NP + off);
        const short8 a2 = *(const short8*)(aBase + (size_t)32 * NP + off);

        // B-frag: col = l&15 = proposal, k = kg*8+j -> 8 bitmap bits
        const int lp0 = off + kg * 8;
        const u32t bits8 =
            (u32t)((sh.a.mwin[l & 15][lp0 >> 6] >> (lp0 & 63)) & 0xFFull);
        union { u32t u[4]; short8 s; } bb;
#pragma unroll
        for (int jj = 0; jj < 4; ++jj)
            bb.u[jj] = (((bits8 >> (2 * jj)) & 1u) ? 0x3F80u : 0u) |
                       (((bits8 >> (2 * jj + 1)) & 1u) ? 0x3F800000u : 0u);

        acc0 = __builtin_amdgcn_mfma_f32_16x16x32_bf16(a0, bb.s, acc0, 0, 0, 0);
        acc1 = __builtin_amdgcn_mfma_f32_16x16x32_bf16(a1, bb.s, acc1, 0, 0, 0);
        acc2 = __builtin_amdgcn_mfma_f32_16x16x32_bf16(a2, bb.s, acc2, 0, 0, 0);
    }

    // ---- cross-wave reduce: D col = l&15 = proposal, row = kg*4+j = ch ----
#pragma unroll
    for (int j = 0; j < 4; ++j) {
        sh.a.red[wv][0][kg * 4 + j][l & 15] = acc0[j];
        sh.a.red[wv][1][kg * 4 + j][l & 15] = acc1[j];
        sh.a.red[wv][2][kg * 4 + j][l & 15] = acc2[j];
    }
    __syncthreads();

    for (int i = t; i < 768; i += 256) {
        const int ct  = i >> 8;
        const int rem = i & 255;
        const int row = rem >> 4;
        const int col = rem & 15;
        const int chg = ct * 16 + row;
        if (chg < 2 * NCLS) {
            const float v = sh.a.red[0][ct][row][col] + sh.a.red[1][ct][row][col] +
                            sh.a.red[2][ct][row][col] + sh.a.red[3][ct][row][col];
            atomicAdd(&gacc[(p0 + col) * ACC_STRIDE + chg], v);
        }
    }
    if (t < 16) {
        int c = 0;
#pragma unroll 1
        for (int w = 0; w < SEG_WORDS; ++w) c += __popcll(sh.a.mwin[t][w]);
        atomicAdd(&gacc[(p0 + t) * ACC_STRIDE + 42], (float)c);
    }
    __syncthreads();

    // ---- last-block-done election ----
    if (t == 0) {
        __threadfence();
        const u32t prev = atomicAdd(done, 1u);
        isLast = (prev == ROIB_BLOCKS - 1) ? 1 : 0;
    }
    __syncthreads();
    if (!isLast) return;

    // ================= fused softmax (last block only) =================
    const int cc = t & 31;
    const int g = t >> 5;

    float v[ACC_STRIDE];
#pragma unroll
    for (int j = 0; j < ACC_STRIDE; ++j) {
        const u32t raw = __hip_atomic_load((const u32t*)&gacc[t * ACC_STRIDE + j],
                                           __ATOMIC_RELAXED, __HIP_MEMORY_SCOPE_AGENT);
        v[j] = __uint_as_float(raw);
    }

    const float cntv = fmaxf(v[42], 1.0f);
    const float rinv = 1.0f / cntv;

    float cl[NCLS], ob[NCLS];
#pragma unroll
    for (int c = 0; c < NCLS; ++c) {
        cl[c] = v[c] * rinv + bc[c];
        ob[c] = v[NCLS + c] * rinv + bo[c];
        sh.b.objl[t][c] = ob[c];
    }
    __syncthreads();

    float m = -INFINITY;
    if (cc < NCLS) {
        const int q0 = g * 32;
        for (int pp = q0; pp < q0 + 32; ++pp) m = fmaxf(m, sh.b.objl[pp][cc]);
    }
    sh.b.red8[g][cc] = m;
    __syncthreads();
    if (t < NCLS) {
        float mm = sh.b.red8[0][t];
#pragma unroll
        for (int gg = 1; gg < 8; ++gg) mm = fmaxf(mm, sh.b.red8[gg][t]);
        sh.b.colmax[t] = mm;
    }
    __syncthreads();

    float sc = 0.0f;
    if (cc < NCLS) {
        const float mm = sh.b.colmax[cc];
        const int q0 = g * 32;
        for (int pp = q0; pp < q0 + 32; ++pp) sc += expf(sh.b.objl[pp][cc] - mm);
    }
    sh.b.red8[g][cc] = sc;
    __syncthreads();
    if (t < NCLS) {
        float ss = sh.b.red8[0][t];
#pragma unroll
        for (int gg = 1; gg < 8; ++gg) ss += sh.b.red8[gg][t];
        sh.b.colsum[t] = ss;
    }

    float rm = cl[0];
#pragma unroll
    for (int c = 1; c < NCLS; ++c) rm = fmaxf(rm, cl[c]);
    float e[NCLS];
    float rs = 0.0f;
#pragma unroll
    for (int c = 0; c < NCLS; ++c) { e[c] = expf(cl[c] - rm); rs += e[c]; }
    const float inv = 1.0f / rs;

    __syncthreads();

#pragma unroll
    for (int c = 0; c < NCLS; ++c) {
        const float cp = e[c] * inv;
        const float op = expf(ob[c] - sh.b.colmax[c]) / sh.b.colsum[c];
        out[t * NCLS + c] = cp * op;
    }
}

// ---------------- launch ----------------------------------------------------
extern "C" void kernel_launch(void* const* d_in, const int* in_sizes, int n_in,
                              void* d_out, int out_size, void* d_ws, size_t ws_size,
                              hipStream_t stream) {
    const float* proposals = (const float*)d_in[0];  // (256,6)
    const float* xyz       = (const float*)d_in[1];  // (100000,3)
    const float* feats     = (const float*)d_in[2];  // (100000,256)
    const float* Wc        = (const float*)d_in[3];  // (256,21)
    const float* bc        = (const float*)d_in[4];  // (21)
    const float* Wo        = (const float*)d_in[5];  // (256,21)
    const float* bo        = (const float*)d_in[6];  // (21)
    float* out = (float*)d_out;                      // (256,21)

    char* ws = (char*)d_ws;
    u16t* fwT    = (u16t*)(ws);                        // 48*100352*2 = 9,633,792 B
    float* gacc  = (float*)(ws + 9633792);             // 45,056 B
    u64t* bm     = (u64t*)(ws + 9633792 + 45056);      // 3,211,264 B
    u32t* done   = (u32t*)(ws + 12890112);             // 64 B slot
    u16t* bfragG = (u16t*)(ws + 12890176);             // 24,576 B

    prep_kernel<<<PREP_BLOCKS, 256, 0, stream>>>(Wc, Wo, bfragG, gacc, fwT, done);
    featw_mask_kernel<<<FEATW_BLOCKS + MASK_BLOCKS, 256, 0, stream>>>(
        proposals, xyz, feats, bfragG, fwT, bm);
    mfma_sum_softmax_kernel<<<ROIB_BLOCKS, 256, 0, stream>>>(
        bm, fwT, gacc, done, bc, bo, out);
}

// Round 8
// 240.313 us; speedup vs baseline: 1.3030x; 1.0002x over previous
//
#include <hip/hip_runtime.h>
#include <math.h>

#define N_PTS 100000
#define P_PROP 256
#define R_FEAT 256
#define NCLS 21          // C + 1
#define NSEG 32          // segments of 3136 points
#define SEG_LEN 3136     // 64-aligned; NSEG*SEG_LEN = 100352 (pad bits/values = 0)
#define NP 100352        // padded point count = fwT row stride
#define SEG_WORDS (SEG_LEN / 64)            // 49
#define BM_WORDS (NSEG * SEG_WORDS)         // 1568 u64 words per proposal
#define ACC_STRIDE 44    // 42 channel sums + 1 count + 1 pad
#define FW3_BLOCKS (NP / 64)                // 1568 featw blocks of 64 rows
#define NFRAG (3 * 8 * 64)   // B fragments: 3 N-tiles x 8 K-steps x 64 lanes
#define MASK_BLOCKS (NSEG * SEG_LEN / 256)  // 392
#define ROIB_BLOCKS 512      // 32 segments x 16 proposal-tiles
#define PREP_BLOCKS 8
#define ALD 264          // aL row stride in bf16: 528B = 16B-aligned, bank-spread

typedef unsigned short u16t;
typedef unsigned int u32t;
typedef unsigned long long u64t;
typedef __attribute__((ext_vector_type(8))) short short8;   // 8 bf16 (4 VGPRs)
typedef __attribute__((ext_vector_type(4))) float f32x4;    // MFMA accumulator

__device__ __forceinline__ u16t f2bf_rne(float x) {
    u32t u = __float_as_uint(x);
    u += 0x7fffu + ((u >> 16) & 1u);
    return (u16t)(u >> 16);
}

// ---------------- Kernel P: B-frag image + zero gacc/done/fwT-pad ----------
// 8 blocks, grid-stride. Builds the pre-swizzled bf16 [Wc|Wo|pad] fragment
// image once (featw reads it from L1/L2), zeroes gacc/done/fwT-pad.
__global__ __launch_bounds__(256) void prep_kernel(
    const float* __restrict__ Wc,      // (R,21)
    const float* __restrict__ Wo,      // (R,21)
    u16t* __restrict__ bfragG,         // (NFRAG*8) bf16 = 24576 B
    float* __restrict__ gacc,          // (P,44) zeroed
    u16t* __restrict__ fwT,            // pad columns [N_PTS,NP) zeroed
    u32t* __restrict__ done)           // zeroed
{
    const int g0 = blockIdx.x * 256 + threadIdx.x;
    const int gs = PREP_BLOCKS * 256;

    if (g0 == 0) *done = 0u;
    for (int i = g0; i < P_PROP * ACC_STRIDE; i += gs) gacc[i] = 0.0f;
    for (int i = g0; i < 48 * 176; i += gs) {         // 352 pad pts x 48 ch (u32 pairs)
        const int chn = i / 176;
        const int o   = i - chn * 176;
        *(u32t*)(fwT + (size_t)chn * NP + N_PTS + o * 2) = 0u;
    }

    for (int idx = g0; idx < NFRAG; idx += gs) {
        const int n   = idx >> 9;         // N-tile 0..2
        const int rem = idx & 511;
        const int kk  = rem >> 6;         // K-step 0..7
        const int l   = rem & 63;         // lane
        const int krow = kk * 32 + (l >> 4) * 8;
        const int c    = n * 16 + (l & 15);
        u32t w[4];
#pragma unroll
        for (int jj = 0; jj < 4; ++jj) {
            const int k0 = krow + 2 * jj;
            float v0 = 0.0f, v1 = 0.0f;
            if (c < NCLS) {
                v0 = Wc[k0 * NCLS + c];
                v1 = Wc[(k0 + 1) * NCLS + c];
            } else if (c < 2 * NCLS) {
                v0 = Wo[k0 * NCLS + (c - NCLS)];
                v1 = Wo[(k0 + 1) * NCLS + (c - NCLS)];
            }
            w[jj] = (u32t)f2bf_rne(v0) | ((u32t)f2bf_rne(v1) << 16);
        }
        *(uint4*)(&bfragG[idx * 8]) = make_uint4(w[0], w[1], w[2], w[3]);
    }
}

// ---------------- Kernel A: featw (LDS-staged MFMA) + mask bitmap ----------
// Round-7 lesson: every featw variant read A-fragments directly from feats
// with 16-rows-at-1KB-stride per wave-load -> DRAM page thrash capped HBM at
// ~850 GB/s (measured rounds 1/6/7) = the whole 77us. v3 decouples the
// global pattern from the fragment layout: blocks [0,1568) stage a 64-row
// A-panel with 16 LINEAR float4 loads/thread (64KB contiguous per block),
// bf16-convert in regs, ds_write to aL[64][264] (528B stride: 16B-aligned
// b128 reads at the LDS floor, conflict-free writes); each wave then MFMAs
// one 16-row m-tile x 3 n-tiles reading A-frags from LDS and B-frags from
// the L1-resident prep image. Blocks [1568,1960): mask bitmap (unchanged).
__global__ __launch_bounds__(256) void featw_mask_kernel(
    const float* __restrict__ proposals,   // (P,6)
    const float* __restrict__ xyz,         // (N,3)
    const float* __restrict__ feats,       // (N,R)
    const u16t* __restrict__ bfragG,       // prep image
    u16t* __restrict__ fwT,                // (48, NP) bf16, channel-major
    u64t* __restrict__ bm)                 // (P, BM_WORDS)
{
    const int t = threadIdx.x;

    __shared__ union {
        u16t   aL[64][ALD];                // featw: 33792 B
        float4 plohi[P_PROP][2];           // mask:   8192 B
    } sh;

    if (blockIdx.x < FW3_BLOCKS) {
        // ================= featw role =================
        const int rowbase = blockIdx.x * 64;

        // ---- stage: 16 reps x coalesced float4 (block reads 64KB linear) --
#pragma unroll
        for (int rep = 0; rep < 16; ++rep) {
            const int o = rep * 1024 + t * 4;      // float offset in 64x256 panel
            const int R = o >> 8;                  // 0..63
            const int C = o & 255;                 // multiple of 4
            const int rg = rowbase + R;
            const int rc = rg < N_PTS ? rg : N_PTS - 1;   // clamp (pad rows masked in B)
            const float4 v = *(const float4*)(feats + (size_t)rc * R_FEAT + C);
            uint2 w;
            w.x = (u32t)f2bf_rne(v.x) | ((u32t)f2bf_rne(v.y) << 16);
            w.y = (u32t)f2bf_rne(v.z) | ((u32t)f2bf_rne(v.w) << 16);
            *(uint2*)(&sh.aL[R][C]) = w;           // 8B-aligned (528*R + 2C)
        }
        __syncthreads();

        // ---- compute: wave wv = m-tile wv (16 rows), 3 n-tiles ----
        const int wv  = t >> 6;
        const int l   = t & 63;
        const int r15 = l & 15;
        const int kg  = l >> 4;

        f32x4 c0 = {0.f,0.f,0.f,0.f};
        f32x4 c1 = {0.f,0.f,0.f,0.f};
        f32x4 c2 = {0.f,0.f,0.f,0.f};

#pragma unroll
        for (int kk = 0; kk < 8; ++kk) {
            const short8 av = *(const short8*)(&sh.aL[wv * 16 + r15][kk * 32 + kg * 8]);
            const short8 b0 = *(const short8*)(&bfragG[((0 * 8 + kk) * 64 + l) * 8]);
            const short8 b1 = *(const short8*)(&bfragG[((1 * 8 + kk) * 64 + l) * 8]);
            const short8 b2 = *(const short8*)(&bfragG[((2 * 8 + kk) * 64 + l) * 8]);
            c0 = __builtin_amdgcn_mfma_f32_16x16x32_bf16(av, b0, c0, 0, 0, 0);
            c1 = __builtin_amdgcn_mfma_f32_16x16x32_bf16(av, b1, c1, 0, 0, 0);
            c2 = __builtin_amdgcn_mfma_f32_16x16x32_bf16(av, b2, c2, 0, 0, 0);
        }

        // ---- transposed epilogue: D col = r15 = channel-in-tile,
        //      row = kg*4 + j = point offset; 4 consecutive pts -> uint2.
        //      pt0+3 <= 100351 < NP always; pad-pt values are masked in B.
        const int pt0 = rowbase + wv * 16 + kg * 4;
        *(uint2*)(fwT + (size_t)r15 * NP + pt0) = make_uint2(
            (u32t)f2bf_rne(c0[0]) | ((u32t)f2bf_rne(c0[1]) << 16),
            (u32t)f2bf_rne(c0[2]) | ((u32t)f2bf_rne(c0[3]) << 16));
        *(uint2*)(fwT + (size_t)(r15 + 16) * NP + pt0) = make_uint2(
            (u32t)f2bf_rne(c1[0]) | ((u32t)f2bf_rne(c1[1]) << 16),
            (u32t)f2bf_rne(c1[2]) | ((u32t)f2bf_rne(c1[3]) << 16));
        *(uint2*)(fwT + (size_t)(r15 + 32) * NP + pt0) = make_uint2(
            (u32t)f2bf_rne(c2[0]) | ((u32t)f2bf_rne(c2[1]) << 16),
            (u32t)f2bf_rne(c2[2]) | ((u32t)f2bf_rne(c2[3]) << 16));
        return;
    }

    // ================= mask role =================
    const int mb = blockIdx.x - FW3_BLOCKS;   // 0..391
    for (int pp = t; pp < P_PROP; pp += 256) {
        const float cx = proposals[pp * 6 + 0];
        const float cy = proposals[pp * 6 + 1];
        const float cz = proposals[pp * 6 + 2];
        const float hx = proposals[pp * 6 + 3] * 0.5f;
        const float hy = proposals[pp * 6 + 4] * 0.5f;
        const float hz = proposals[pp * 6 + 5] * 0.5f;
        sh.plohi[pp][0] = make_float4(cx - hx, cy - hy, cz - hz, cx + hx);
        sh.plohi[pp][1] = make_float4(cy + hy, cz + hz, 0.0f, 0.0f);
    }
    __syncthreads();

    const int i = mb * 256 + t;
    const bool alive = i < N_PTS;
    const int ic = alive ? i : 0;
    const float xx = xyz[ic * 3 + 0];
    const float yy = xyz[ic * 3 + 1];
    const float zz = xyz[ic * 3 + 2];
    const int lane = t & 63;
    const int iw = mb * 4 + (t >> 6);      // global u64 word index for this wave

#pragma unroll 8
    for (int p = 0; p < P_PROP; ++p) {
        const float4 a = sh.plohi[p][0];
        const float4 b = sh.plohi[p][1];
        const bool in = alive &
                        (xx >= a.x) & (xx <= a.w) &
                        (yy >= a.y) & (yy <= b.x) &
                        (zz >= a.z) & (zz <= b.y);
        const u64t msk = __ballot(in);
        if (lane == 0) bm[(size_t)p * BM_WORDS + iw] = msk;
    }
}

// ---------------- Kernel B: ROI-sum as MFMA + atomic combine + softmax -----
// Unchanged (passed rounds 6-7). roisum = mask @ fW with mask B-frags
// synthesized in registers from the bitmap; last-done block runs the softmax
// with agent-scope gacc loads (G16).
__global__ __launch_bounds__(256) void mfma_sum_softmax_kernel(
    const u64t* __restrict__ bm,           // (P, BM_WORDS)
    const u16t* __restrict__ fwT,          // (48, NP) bf16
    float* __restrict__ gacc,              // (P,44)
    u32t* __restrict__ done,
    const float* __restrict__ bc,          // (21)
    const float* __restrict__ bo,          // (21)
    float* __restrict__ out)               // (P,21)
{
    const int bid   = blockIdx.x;
    const int seg   = (bid & 7) + 8 * (bid >> 7);   // XCD = seg%8
    const int ptile = (bid >> 3) & 15;
    const int p0    = ptile * 16;

    const int t  = threadIdx.x;
    const int wv = t >> 6;
    const int l  = t & 63;

    __shared__ union {
        struct {                            // MFMA phase
            u64t  mwin[16][SEG_WORDS];      // 6272 B
            float red[4][3][16][16];        // 12288 B
        } a;
        struct {                            // softmax phase (barrier-separated)
            float objl[P_PROP][NCLS];       // 21504 B
            float red8[8][32];
            float colmax[32];
            float colsum[32];
        } b;
    } sh;
    __shared__ int isLast;

    // ---- stage this block's bitmap window: 16 proposals x 49 u64 ----
    for (int i = t; i < 16 * SEG_WORDS; i += 256) {
        const int pi = i / SEG_WORDS;
        const int w  = i - pi * SEG_WORDS;
        sh.a.mwin[pi][w] = bm[(size_t)(p0 + pi) * BM_WORDS + seg * SEG_WORDS + w];
    }
    __syncthreads();

    // ---- MFMA K-loop: 98 k-steps of 32 points split 25/25/24/24 ----
    const int ks0 = wv * 24 + (wv < 2 ? wv : 2);
    const int ks1 = ks0 + (wv < 2 ? 25 : 24);

    const int ch = l & 15;                 // A row (channel within tile)
    const int kg = l >> 4;                 // k-group 0..3
    const u16t* __restrict__ aBase =
        fwT + (size_t)ch * NP + (size_t)seg * SEG_LEN + kg * 8;

    f32x4 acc0 = {0.f,0.f,0.f,0.f};
    f32x4 acc1 = {0.f,0.f,0.f,0.f};
    f32x4 acc2 = {0.f,0.f,0.f,0.f};

#pragma unroll 1
    for (int ks = ks0; ks < ks1; ++ks) {
        const int off = ks * 32;
        const short8 a0 = *(const short8*)(aBase + off);
        const short8 a1 = *(const short8*)(aBase + (size_t)16 * NP + off);
        const short8 a2 = *(const short8*)(aBase + (size_t)32 * NP + off);

        // B-frag: col = l&15 = proposal, k = kg*8+j -> 8 bitmap bits
        const int lp0 = off + kg * 8;
        const u32t bits8 =
            (u32t)((sh.a.mwin[l & 15][lp0 >> 6] >> (lp0 & 63)) & 0xFFull);
        union { u32t u[4]; short8 s; } bb;
#pragma unroll
        for (int jj = 0; jj < 4; ++jj)
            bb.u[jj] = (((bits8 >> (2 * jj)) & 1u) ? 0x3F80u : 0u) |
                       (((bits8 >> (2 * jj + 1)) & 1u) ? 0x3F800000u : 0u);

        acc0 = __builtin_amdgcn_mfma_f32_16x16x32_bf16(a0, bb.s, acc0, 0, 0, 0);
        acc1 = __builtin_amdgcn_mfma_f32_16x16x32_bf16(a1, bb.s, acc1, 0, 0, 0);
        acc2 = __builtin_amdgcn_mfma_f32_16x16x32_bf16(a2, bb.s, acc2, 0, 0, 0);
    }

    // ---- cross-wave reduce: D col = l&15 = proposal, row = kg*4+j = ch ----
#pragma unroll
    for (int j = 0; j < 4; ++j) {
        sh.a.red[wv][0][kg * 4 + j][l & 15] = acc0[j];
        sh.a.red[wv][1][kg * 4 + j][l & 15] = acc1[j];
        sh.a.red[wv][2][kg * 4 + j][l & 15] = acc2[j];
    }
    __syncthreads();

    for (int i = t; i < 768; i += 256) {
        const int ct  = i >> 8;
        const int rem = i & 255;
        const int row = rem >> 4;
        const int col = rem & 15;
        const int chg = ct * 16 + row;
        if (chg < 2 * NCLS) {
            const float v = sh.a.red[0][ct][row][col] + sh.a.red[1][ct][row][col] +
                            sh.a.red[2][ct][row][col] + sh.a.red[3][ct][row][col];
            atomicAdd(&gacc[(p0 + col) * ACC_STRIDE + chg], v);
        }
    }
    if (t < 16) {
        int c = 0;
#pragma unroll 1
        for (int w = 0; w < SEG_WORDS; ++w) c += __popcll(sh.a.mwin[t][w]);
        atomicAdd(&gacc[(p0 + t) * ACC_STRIDE + 42], (float)c);
    }
    __syncthreads();

    // ---- last-block-done election ----
    if (t == 0) {
        __threadfence();
        const u32t prev = atomicAdd(done, 1u);
        isLast = (prev == ROIB_BLOCKS - 1) ? 1 : 0;
    }
    __syncthreads();
    if (!isLast) return;

    // ================= fused softmax (last block only) =================
    const int cc = t & 31;
    const int g = t >> 5;

    float v[ACC_STRIDE];
#pragma unroll
    for (int j = 0; j < ACC_STRIDE; ++j) {
        const u32t raw = __hip_atomic_load((const u32t*)&gacc[t * ACC_STRIDE + j],
                                           __ATOMIC_RELAXED, __HIP_MEMORY_SCOPE_AGENT);
        v[j] = __uint_as_float(raw);
    }

    const float cntv = fmaxf(v[42], 1.0f);
    const float rinv = 1.0f / cntv;

    float cl[NCLS], ob[NCLS];
#pragma unroll
    for (int c = 0; c < NCLS; ++c) {
        cl[c] = v[c] * rinv + bc[c];
        ob[c] = v[NCLS + c] * rinv + bo[c];
        sh.b.objl[t][c] = ob[c];
    }
    __syncthreads();

    float m = -INFINITY;
    if (cc < NCLS) {
        const int q0 = g * 32;
        for (int pp = q0; pp < q0 + 32; ++pp) m = fmaxf(m, sh.b.objl[pp][cc]);
    }
    sh.b.red8[g][cc] = m;
    __syncthreads();
    if (t < NCLS) {
        float mm = sh.b.red8[0][t];
#pragma unroll
        for (int gg = 1; gg < 8; ++gg) mm = fmaxf(mm, sh.b.red8[gg][t]);
        sh.b.colmax[t] = mm;
    }
    __syncthreads();

    float sc = 0.0f;
    if (cc < NCLS) {
        const float mm = sh.b.colmax[cc];
        const int q0 = g * 32;
        for (int pp = q0; pp < q0 + 32; ++pp) sc += expf(sh.b.objl[pp][cc] - mm);
    }
    sh.b.red8[g][cc] = sc;
    __syncthreads();
    if (t < NCLS) {
        float ss = sh.b.red8[0][t];
#pragma unroll
        for (int gg = 1; gg < 8; ++gg) ss += sh.b.red8[gg][t];
        sh.b.colsum[t] = ss;
    }

    float rm = cl[0];
#pragma unroll
    for (int c = 1; c < NCLS; ++c) rm = fmaxf(rm, cl[c]);
    float e[NCLS];
    float rs = 0.0f;
#pragma unroll
    for (int c = 0; c < NCLS; ++c) { e[c] = expf(cl[c] - rm); rs += e[c]; }
    const float inv = 1.0f / rs;

    __syncthreads();

#pragma unroll
    for (int c = 0; c < NCLS; ++c) {
        const float cp = e[c] * inv;
        const float op = expf(ob[c] - sh.b.colmax[c]) / sh.b.colsum[c];
        out[t * NCLS + c] = cp * op;
    }
}

// ---------------- launch ----------------------------------------------------
extern "C" void kernel_launch(void* const* d_in, const int* in_sizes, int n_in,
                              void* d_out, int out_size, void* d_ws, size_t ws_size,
                              hipStream_t stream) {
    const float* proposals = (const float*)d_in[0];  // (256,6)
    const float* xyz       = (const float*)d_in[1];  // (100000,3)
    const float* feats     = (const float*)d_in[2];  // (100000,256)
    const float* Wc        = (const float*)d_in[3];  // (256,21)
    const float* bc        = (const float*)d_in[4];  // (21)
    const float* Wo        = (const float*)d_in[5];  // (256,21)
    const float* bo        = (const float*)d_in[6];  // (21)
    float* out = (float*)d_out;                      // (256,21)

    char* ws = (char*)d_ws;
    u16t* fwT    = (u16t*)(ws);                        // 48*100352*2 = 9,633,792 B
    float* gacc  = (float*)(ws + 9633792);             // 45,056 B
    u64t* bm     = (u64t*)(ws + 9633792 + 45056);      // 3,211,264 B
    u32t* done   = (u32t*)(ws + 12890112);             // 64 B slot
    u16t* bfragG = (u16t*)(ws + 12890176);             // 24,576 B

    prep_kernel<<<PREP_BLOCKS, 256, 0, stream>>>(Wc, Wo, bfragG, gacc, fwT, done);
    featw_mask_kernel<<<FW3_BLOCKS + MASK_BLOCKS, 256, 0, stream>>>(
        proposals, xyz, feats, bfragG, fwT, bm);
    mfma_sum_softmax_kernel<<<ROIB_BLOCKS, 256, 0, stream>>>(
        bm, fwT, gacc, done, bc, bo, out);
}